// Round 1
// baseline (626.125 us; speedup 1.0000x reference)
//
#include <hip/hip_runtime.h>
#include <hip/hip_bf16.h>
#include <stdint.h>

#define DM 1024
#define DKH 64
#define NH 16
#define NB 4
#define SEQ 2048

typedef __attribute__((ext_vector_type(8))) short bf16x8;
typedef __attribute__((ext_vector_type(8))) unsigned short ushort8;
typedef __attribute__((ext_vector_type(4))) float f32x4;

__device__ inline unsigned short f2bf(float f) {
  union { float f; unsigned u; } c; c.f = f;
  unsigned u = c.u;
  u += 0x7fff + ((u >> 16) & 1);   // round-to-nearest-even
  return (unsigned short)(u >> 16);
}

// ---------- weight transpose + cast: Wt[n][k] = bf16(W[k][n]), 1024x1024 ----------
__global__ __launch_bounds__(256) void wcast_t(const float* __restrict__ W,
                                               unsigned short* __restrict__ Wt) {
  __shared__ float tile[32][33];
  int bk = blockIdx.x * 32, bn = blockIdx.y * 32;
  int tx = threadIdx.x & 31, ty = threadIdx.x >> 5;  // ty 0..7
#pragma unroll
  for (int i = 0; i < 4; ++i)
    tile[ty + 8 * i][tx] = W[(size_t)(bk + ty + 8 * i) * DM + bn + tx];
  __syncthreads();
#pragma unroll
  for (int i = 0; i < 4; ++i)
    Wt[(size_t)(bn + ty + 8 * i) * DM + bk + tx] = f2bf(tile[tx][ty + 8 * i]);
}

// ---------- 128x128 tile bf16 GEMM, M=8192 N=1024 K=1024 ----------
// EPI: 0 = bf16 out, [B,H,S,64] layout (Q/K), value=(acc+bias)*scale
//      1 = bf16 out, [B,H,64,S] layout (V transposed)
//      2 = fp32 out, row-major [M][N] (final projection)
// ABF16: 1 -> A operand is bf16 (unsigned short), 0 -> fp32 (cast during staging)
template <int EPI, int ABF16>
__global__ __launch_bounds__(256) void gemm128(const void* __restrict__ Av,
                                               const unsigned short* __restrict__ Bt,
                                               const float* __restrict__ bias,
                                               void* __restrict__ Cv, float scale) {
  __shared__ __align__(16) unsigned short As[128][32];
  __shared__ __align__(16) unsigned short Bs[128][32];
  const int K = DM;
  int t = threadIdx.x;
  int wave = t >> 6, lane = t & 63;
  int wr = wave >> 1, wc = wave & 1;
  int l15 = lane & 15, g = lane >> 4;
  int tm = blockIdx.x >> 3, tn = blockIdx.x & 7;  // N/128 = 8
  int rowBase = tm * 128, colBase = tn * 128;

  f32x4 acc[4][4];
#pragma unroll
  for (int mi = 0; mi < 4; ++mi)
#pragma unroll
    for (int ni = 0; ni < 4; ++ni) acc[mi][ni] = (f32x4){0.f, 0.f, 0.f, 0.f};

  int srow = t >> 2;        // 0..63
  int skb = (t & 3) * 8;    // 0,8,16,24

  for (int kt = 0; kt < K; kt += 32) {
    __syncthreads();
#pragma unroll
    for (int i = 0; i < 2; ++i) {
      int row = srow + i * 64;
      if (ABF16) {
        ushort8 v = *reinterpret_cast<const ushort8*>(
            (const unsigned short*)Av + (size_t)(rowBase + row) * K + kt + skb);
        *reinterpret_cast<ushort8*>(&As[row][skb]) = v;
      } else {
        const float* Af = (const float*)Av + (size_t)(rowBase + row) * K + kt + skb;
        float4 x = *reinterpret_cast<const float4*>(Af);
        float4 y = *reinterpret_cast<const float4*>(Af + 4);
        ushort8 v;
        v[0] = f2bf(x.x); v[1] = f2bf(x.y); v[2] = f2bf(x.z); v[3] = f2bf(x.w);
        v[4] = f2bf(y.x); v[5] = f2bf(y.y); v[6] = f2bf(y.z); v[7] = f2bf(y.w);
        *reinterpret_cast<ushort8*>(&As[row][skb]) = v;
      }
      ushort8 w = *reinterpret_cast<const ushort8*>(
          Bt + (size_t)(colBase + row) * K + kt + skb);
      *reinterpret_cast<ushort8*>(&Bs[row][skb]) = w;
    }
    __syncthreads();

    bf16x8 af[4], bfr[4];
#pragma unroll
    for (int mi = 0; mi < 4; ++mi)
      af[mi] = *reinterpret_cast<const bf16x8*>(&As[wr * 64 + mi * 16 + l15][g * 8]);
#pragma unroll
    for (int ni = 0; ni < 4; ++ni)
      bfr[ni] = *reinterpret_cast<const bf16x8*>(&Bs[wc * 64 + ni * 16 + l15][g * 8]);
#pragma unroll
    for (int mi = 0; mi < 4; ++mi)
#pragma unroll
      for (int ni = 0; ni < 4; ++ni)
        acc[mi][ni] = __builtin_amdgcn_mfma_f32_16x16x32_bf16(af[mi], bfr[ni],
                                                              acc[mi][ni], 0, 0, 0);
  }

#pragma unroll
  for (int ni = 0; ni < 4; ++ni) {
    int col = colBase + wc * 64 + ni * 16 + l15;
    float bv = bias[col];
#pragma unroll
    for (int mi = 0; mi < 4; ++mi) {
#pragma unroll
      for (int r = 0; r < 4; ++r) {
        int row = rowBase + wr * 64 + mi * 16 + g * 4 + r;
        float val = (acc[mi][ni][r] + bv) * scale;
        if (EPI == 0) {
          int b_ = row >> 11, s_ = row & 2047;
          int h_ = col >> 6, d_ = col & 63;
          ((unsigned short*)Cv)[(size_t)((b_ * NH + h_) * SEQ + s_) * DKH + d_] = f2bf(val);
        } else if (EPI == 1) {
          int b_ = row >> 11, s_ = row & 2047;
          int h_ = col >> 6, d_ = col & 63;
          ((unsigned short*)Cv)[(size_t)((b_ * NH + h_) * DKH + d_) * SEQ + s_] = f2bf(val);
        } else {
          ((float*)Cv)[(size_t)row * DM + col] = val;
        }
      }
    }
  }
}

// ---------- flash attention: Q,K [BH][S][64] bf16 (Q pre-scaled by 0.125*log2e),
// Vt [BH][64][S] bf16, AO [B][S][H*64] bf16 ----------
__global__ __launch_bounds__(256) void attn_fwd(const unsigned short* __restrict__ Qb,
                                                const unsigned short* __restrict__ Kb,
                                                const unsigned short* __restrict__ Vt,
                                                unsigned short* __restrict__ AO) {
  __shared__ __align__(16) unsigned short Plds[4][16][32];
  int t = threadIdx.x;
  int wave = t >> 6, lane = t & 63;
  int l15 = lane & 15, g = lane >> 4;
  int qtile = blockIdx.x;  // 0..31
  int bh = blockIdx.y;     // 0..63
  const size_t baseQK = (size_t)bh * SEQ * DKH;
  const size_t baseV = (size_t)bh * DKH * SEQ;
  int q0 = qtile * 64 + wave * 16;

  bf16x8 aQ[2];
#pragma unroll
  for (int dh = 0; dh < 2; ++dh)
    aQ[dh] = *reinterpret_cast<const bf16x8*>(Qb + baseQK + (size_t)(q0 + l15) * DKH +
                                              dh * 32 + g * 8);

  float m_r[4], l_r[4];
  f32x4 accO[4];
#pragma unroll
  for (int r = 0; r < 4; ++r) { m_r[r] = -1e30f; l_r[r] = 0.f; }
#pragma unroll
  for (int dt = 0; dt < 4; ++dt) accO[dt] = (f32x4){0.f, 0.f, 0.f, 0.f};

  for (int p = 0; p < SEQ / 32; ++p) {
    int s0 = p * 32;
    f32x4 sc[2];
#pragma unroll
    for (int tt = 0; tt < 2; ++tt) {
      int st = s0 + tt * 16;
      f32x4 z = (f32x4){0.f, 0.f, 0.f, 0.f};
#pragma unroll
      for (int dh = 0; dh < 2; ++dh) {
        bf16x8 bK = *reinterpret_cast<const bf16x8*>(
            Kb + baseQK + (size_t)(st + l15) * DKH + dh * 32 + g * 8);
        z = __builtin_amdgcn_mfma_f32_16x16x32_bf16(aQ[dh], bK, z, 0, 0, 0);
      }
      sc[tt] = z;
    }
    // online softmax, one q-row per (group, r)
#pragma unroll
    for (int r = 0; r < 4; ++r) {
      float v = fmaxf(sc[0][r], sc[1][r]);
      v = fmaxf(v, __shfl_xor(v, 1));
      v = fmaxf(v, __shfl_xor(v, 2));
      v = fmaxf(v, __shfl_xor(v, 4));
      v = fmaxf(v, __shfl_xor(v, 8));
      float mnew = fmaxf(m_r[r], v);
      float alpha = exp2f(m_r[r] - mnew);
      float p0 = exp2f(sc[0][r] - mnew);
      float p1 = exp2f(sc[1][r] - mnew);
      float ps = p0 + p1;
      ps += __shfl_xor(ps, 1);
      ps += __shfl_xor(ps, 2);
      ps += __shfl_xor(ps, 4);
      ps += __shfl_xor(ps, 8);
      l_r[r] = l_r[r] * alpha + ps;
      m_r[r] = mnew;
#pragma unroll
      for (int dt = 0; dt < 4; ++dt) accO[dt][r] *= alpha;
      int qi = g * 4 + r;
      Plds[wave][qi][l15] = f2bf(p0);
      Plds[wave][qi][16 + l15] = f2bf(p1);
    }
    asm volatile("s_waitcnt lgkmcnt(0)" ::: "memory");
    bf16x8 aP = *reinterpret_cast<const bf16x8*>(&Plds[wave][l15][g * 8]);
#pragma unroll
    for (int dt = 0; dt < 4; ++dt) {
      bf16x8 bV = *reinterpret_cast<const bf16x8*>(
          Vt + baseV + (size_t)(dt * 16 + l15) * SEQ + s0 + g * 8);
      accO[dt] = __builtin_amdgcn_mfma_f32_16x16x32_bf16(aP, bV, accO[dt], 0, 0, 0);
    }
  }

  int b_ = bh >> 4, h_ = bh & 15;
#pragma unroll
  for (int r = 0; r < 4; ++r) {
    float inv = 1.f / l_r[r];
    int sq = q0 + g * 4 + r;
#pragma unroll
    for (int dt = 0; dt < 4; ++dt) {
      float val = accO[dt][r] * inv;
      AO[(size_t)(b_ * SEQ + sq) * DM + h_ * DKH + dt * 16 + l15] = f2bf(val);
    }
  }
}

extern "C" void kernel_launch(void* const* d_in, const int* in_sizes, int n_in,
                              void* d_out, int out_size, void* d_ws, size_t ws_size,
                              hipStream_t stream) {
  (void)in_sizes; (void)n_in; (void)out_size; (void)ws_size;
  const float* queries = (const float*)d_in[0];
  const float* keys = (const float*)d_in[1];
  const float* values = (const float*)d_in[2];
  const float* Wq = (const float*)d_in[3];
  const float* bq = (const float*)d_in[4];
  const float* Wk = (const float*)d_in[5];
  const float* bk = (const float*)d_in[6];
  const float* Wv = (const float*)d_in[7];
  const float* bv = (const float*)d_in[8];
  const float* Wo = (const float*)d_in[9];
  const float* bo = (const float*)d_in[10];
  float* out = (float*)d_out;

  char* ws = (char*)d_ws;
  unsigned short* wt_q = (unsigned short*)(ws + 0 * (1u << 21));
  unsigned short* wt_k = (unsigned short*)(ws + 1 * (1u << 21));
  unsigned short* wt_v = (unsigned short*)(ws + 2 * (1u << 21));
  unsigned short* wt_o = (unsigned short*)(ws + 3 * (1u << 21));
  unsigned short* Qb = (unsigned short*)(ws + (8u << 20));
  unsigned short* Kb = (unsigned short*)(ws + (24u << 20));
  unsigned short* Vt = (unsigned short*)(ws + (40u << 20));
  unsigned short* AO = (unsigned short*)(ws + (56u << 20));
  // total ws use: 72 MiB

  dim3 tgrid(32, 32);
  wcast_t<<<tgrid, 256, 0, stream>>>(Wq, wt_q);
  wcast_t<<<tgrid, 256, 0, stream>>>(Wk, wt_k);
  wcast_t<<<tgrid, 256, 0, stream>>>(Wv, wt_v);
  wcast_t<<<tgrid, 256, 0, stream>>>(Wo, wt_o);

  const float SQ = 0.125f * 1.4426950408889634f;  // fold 1/sqrt(64) and log2(e) into Q
  gemm128<0, 0><<<512, 256, 0, stream>>>(queries, wt_q, bq, Qb, SQ);
  gemm128<0, 0><<<512, 256, 0, stream>>>(keys, wt_k, bk, Kb, 1.0f);
  gemm128<1, 0><<<512, 256, 0, stream>>>(values, wt_v, bv, Vt, 1.0f);
  attn_fwd<<<dim3(32, 64), 256, 0, stream>>>(Qb, Kb, Vt, AO);
  gemm128<2, 1><<<512, 256, 0, stream>>>(AO, wt_o, bo, out, 1.0f);
}

// Round 2
// 617.739 us; speedup vs baseline: 1.0136x; 1.0136x over previous
//
#include <hip/hip_runtime.h>
#include <hip/hip_bf16.h>
#include <stdint.h>

#define DM 1024
#define DKH 64
#define NH 16
#define NB 4
#define SEQ 2048

typedef __attribute__((ext_vector_type(8))) short bf16x8;
typedef __attribute__((ext_vector_type(8))) unsigned short ushort8;
typedef __attribute__((ext_vector_type(4))) float f32x4;

__device__ inline unsigned short f2bf(float f) {
  union { float f; unsigned u; } c; c.f = f;
  unsigned u = c.u;
  u += 0x7fff + ((u >> 16) & 1);   // round-to-nearest-even
  return (unsigned short)(u >> 16);
}

// ---------- weight transpose + cast: Wt[n][k] = bf16(W[k][n]), 1024x1024 ----------
__global__ __launch_bounds__(256) void wcast_t(const float* __restrict__ W,
                                               unsigned short* __restrict__ Wt) {
  __shared__ float tile[32][33];
  int bk = blockIdx.x * 32, bn = blockIdx.y * 32;
  int tx = threadIdx.x & 31, ty = threadIdx.x >> 5;  // ty 0..7
#pragma unroll
  for (int i = 0; i < 4; ++i)
    tile[ty + 8 * i][tx] = W[(size_t)(bk + ty + 8 * i) * DM + bn + tx];
  __syncthreads();
#pragma unroll
  for (int i = 0; i < 4; ++i)
    Wt[(size_t)(bn + ty + 8 * i) * DM + bk + tx] = f2bf(tile[tx][ty + 8 * i]);
}

// ---------- 128x128 tile bf16 GEMM, M=8192 N=1024 K=1024 ----------
// EPI: 0 = bf16 out, [B,H,S,64] layout (Q/K), value=(acc+bias)*scale
//      1 = bf16 out, [B,H,64,S] layout (V transposed)
//      2 = fp32 out, row-major [M][N] (final projection)
// ABF16: 1 -> A operand is bf16 (unsigned short), 0 -> fp32 (cast during staging)
template <int EPI, int ABF16>
__global__ __launch_bounds__(256) void gemm128(const void* __restrict__ Av,
                                               const unsigned short* __restrict__ Bt,
                                               const float* __restrict__ bias,
                                               void* __restrict__ Cv, float scale) {
  __shared__ __align__(16) unsigned short As[128][32];
  __shared__ __align__(16) unsigned short Bs[128][32];
  const int K = DM;
  int t = threadIdx.x;
  int wave = t >> 6, lane = t & 63;
  int wr = wave >> 1, wc = wave & 1;
  int l15 = lane & 15, g = lane >> 4;
  int tm = blockIdx.x >> 3, tn = blockIdx.x & 7;  // N/128 = 8
  int rowBase = tm * 128, colBase = tn * 128;

  f32x4 acc[4][4];
#pragma unroll
  for (int mi = 0; mi < 4; ++mi)
#pragma unroll
    for (int ni = 0; ni < 4; ++ni) acc[mi][ni] = (f32x4){0.f, 0.f, 0.f, 0.f};

  int srow = t >> 2;        // 0..63
  int skb = (t & 3) * 8;    // 0,8,16,24

  for (int kt = 0; kt < K; kt += 32) {
    __syncthreads();
#pragma unroll
    for (int i = 0; i < 2; ++i) {
      int row = srow + i * 64;
      if (ABF16) {
        ushort8 v = *reinterpret_cast<const ushort8*>(
            (const unsigned short*)Av + (size_t)(rowBase + row) * K + kt + skb);
        *reinterpret_cast<ushort8*>(&As[row][skb]) = v;
      } else {
        const float* Af = (const float*)Av + (size_t)(rowBase + row) * K + kt + skb;
        float4 x = *reinterpret_cast<const float4*>(Af);
        float4 y = *reinterpret_cast<const float4*>(Af + 4);
        ushort8 v;
        v[0] = f2bf(x.x); v[1] = f2bf(x.y); v[2] = f2bf(x.z); v[3] = f2bf(x.w);
        v[4] = f2bf(y.x); v[5] = f2bf(y.y); v[6] = f2bf(y.z); v[7] = f2bf(y.w);
        *reinterpret_cast<ushort8*>(&As[row][skb]) = v;
      }
      ushort8 w = *reinterpret_cast<const ushort8*>(
          Bt + (size_t)(colBase + row) * K + kt + skb);
      *reinterpret_cast<ushort8*>(&Bs[row][skb]) = w;
    }
    __syncthreads();

    bf16x8 af[4], bfr[4];
#pragma unroll
    for (int mi = 0; mi < 4; ++mi)
      af[mi] = *reinterpret_cast<const bf16x8*>(&As[wr * 64 + mi * 16 + l15][g * 8]);
#pragma unroll
    for (int ni = 0; ni < 4; ++ni)
      bfr[ni] = *reinterpret_cast<const bf16x8*>(&Bs[wc * 64 + ni * 16 + l15][g * 8]);
#pragma unroll
    for (int mi = 0; mi < 4; ++mi)
#pragma unroll
      for (int ni = 0; ni < 4; ++ni)
        acc[mi][ni] = __builtin_amdgcn_mfma_f32_16x16x32_bf16(af[mi], bfr[ni],
                                                              acc[mi][ni], 0, 0, 0);
  }

#pragma unroll
  for (int ni = 0; ni < 4; ++ni) {
    int col = colBase + wc * 64 + ni * 16 + l15;
    float bv = bias[col];
#pragma unroll
    for (int mi = 0; mi < 4; ++mi) {
#pragma unroll
      for (int r = 0; r < 4; ++r) {
        int row = rowBase + wr * 64 + mi * 16 + g * 4 + r;
        float val = (acc[mi][ni][r] + bv) * scale;
        if (EPI == 0) {
          int b_ = row >> 11, s_ = row & 2047;
          int h_ = col >> 6, d_ = col & 63;
          ((unsigned short*)Cv)[(size_t)((b_ * NH + h_) * SEQ + s_) * DKH + d_] = f2bf(val);
        } else if (EPI == 1) {
          int b_ = row >> 11, s_ = row & 2047;
          int h_ = col >> 6, d_ = col & 63;
          ((unsigned short*)Cv)[(size_t)((b_ * NH + h_) * DKH + d_) * SEQ + s_] = f2bf(val);
        } else {
          ((float*)Cv)[(size_t)row * DM + col] = val;
        }
      }
    }
  }
}

// ---------- flash attention (swapped QK^T, lane-local softmax) ----------
// Q,K [BH][S][64] bf16 (Q pre-scaled by 0.125*log2e), Vt [BH][64][S] bf16,
// AO [B][S][H*64] bf16.
// Per wave: 16 q-rows. Score tile computed as mfma(K_frag, Q_frag) so the
// D-layout gives lane (g,l15): P[q = l15][k = g*4 + r]  (k chunk-local).
// Softmax per lane over its 8 scores; row-reduce = 2 shfl_xor (lanes sharing
// l15). P repacked via padded per-wave LDS into the x32 A-operand layout.
__global__ __launch_bounds__(256) void attn_fwd(const unsigned short* __restrict__ Qb,
                                                const unsigned short* __restrict__ Kb,
                                                const unsigned short* __restrict__ Vt,
                                                unsigned short* __restrict__ AO) {
  // row stride 40 shorts = 80 B: 16B-aligned rows, ~2-way (free) bank aliasing
  __shared__ __align__(16) unsigned short Plds[4][16][40];
  int t = threadIdx.x;
  int wave = t >> 6, lane = t & 63;
  int l15 = lane & 15, g = lane >> 4;
  int qtile = blockIdx.x;  // 0..31
  int bh = blockIdx.y;     // 0..63
  const size_t baseQK = (size_t)bh * SEQ * DKH;
  const size_t baseV = (size_t)bh * DKH * SEQ;
  int q0 = qtile * 64 + wave * 16;

  bf16x8 aQ[2];
#pragma unroll
  for (int dh = 0; dh < 2; ++dh)
    aQ[dh] = *reinterpret_cast<const bf16x8*>(Qb + baseQK + (size_t)(q0 + l15) * DKH +
                                              dh * 32 + g * 8);

  float m = -1e30f, lsum = 0.f;
  f32x4 accO[4];
#pragma unroll
  for (int dt = 0; dt < 4; ++dt) accO[dt] = (f32x4){0.f, 0.f, 0.f, 0.f};

  for (int pc = 0; pc < SEQ / 32; ++pc) {
    int s0 = pc * 32;
    // QK^T swapped: A = K rows (k = s0+tt*16+l15), B = Q rows
    f32x4 sc[2];
#pragma unroll
    for (int tt = 0; tt < 2; ++tt) {
      f32x4 z = (f32x4){0.f, 0.f, 0.f, 0.f};
#pragma unroll
      for (int dh = 0; dh < 2; ++dh) {
        bf16x8 kf = *reinterpret_cast<const bf16x8*>(
            Kb + baseQK + (size_t)(s0 + tt * 16 + l15) * DKH + dh * 32 + g * 8);
        z = __builtin_amdgcn_mfma_f32_16x16x32_bf16(kf, aQ[dh], z, 0, 0, 0);
      }
      sc[tt] = z;
    }
    // lane-local max over the 8 scores of q=l15
    float vm = fmaxf(fmaxf(fmaxf(sc[0][0], sc[0][1]), fmaxf(sc[0][2], sc[0][3])),
                     fmaxf(fmaxf(sc[1][0], sc[1][1]), fmaxf(sc[1][2], sc[1][3])));
    vm = fmaxf(vm, __shfl_xor(vm, 16));
    vm = fmaxf(vm, __shfl_xor(vm, 32));  // row-max, uniform across g for fixed l15
    // defer-max (T13): only rescale when the running max grows by >8 (log2 units)
    if (__any(vm > m + 8.f)) {
      float mnew = fmaxf(m, vm);
      float alpha = __builtin_amdgcn_exp2f(m - mnew);
      m = mnew;
      lsum *= alpha;
      float ar[4];
#pragma unroll
      for (int r = 0; r < 4; ++r) ar[r] = __shfl(alpha, g * 4 + r);  // alpha for row q=g*4+r
#pragma unroll
      for (int dt = 0; dt < 4; ++dt)
#pragma unroll
        for (int r = 0; r < 4; ++r) accO[dt][r] *= ar[r];
    }
    float pv[8];
#pragma unroll
    for (int tt = 0; tt < 2; ++tt)
#pragma unroll
      for (int r = 0; r < 4; ++r) pv[tt * 4 + r] = __builtin_amdgcn_exp2f(sc[tt][r] - m);
    lsum += ((pv[0] + pv[1]) + (pv[2] + pv[3])) + ((pv[4] + pv[5]) + (pv[6] + pv[7]));
    // pack P to bf16 pairs and scatter into [q][k] LDS layout
#pragma unroll
    for (int tt = 0; tt < 2; ++tt)
#pragma unroll
      for (int s = 0; s < 2; ++s) {
        unsigned w;
        asm("v_cvt_pk_bf16_f32 %0, %1, %2"
            : "=v"(w)
            : "v"(pv[tt * 4 + 2 * s]), "v"(pv[tt * 4 + 2 * s + 1]));
        *reinterpret_cast<unsigned*>(&Plds[wave][l15][tt * 16 + g * 4 + 2 * s]) = w;
      }
    asm volatile("s_waitcnt lgkmcnt(0)" ::: "memory");
    bf16x8 aP = *reinterpret_cast<const bf16x8*>(&Plds[wave][l15][g * 8]);
#pragma unroll
    for (int dt = 0; dt < 4; ++dt) {
      bf16x8 bV = *reinterpret_cast<const bf16x8*>(
          Vt + baseV + (size_t)(dt * 16 + l15) * SEQ + s0 + g * 8);
      accO[dt] = __builtin_amdgcn_mfma_f32_16x16x32_bf16(aP, bV, accO[dt], 0, 0, 0);
    }
  }

  // final row-sum reduce (once), then output rows q = g*4+r, cols d = dt*16+l15
  lsum += __shfl_xor(lsum, 16);
  lsum += __shfl_xor(lsum, 32);
  int b_ = bh >> 4, h_ = bh & 15;
#pragma unroll
  for (int r = 0; r < 4; ++r) {
    float lr = __shfl(lsum, g * 4 + r);
    float inv = 1.f / lr;
    int sq = q0 + g * 4 + r;
#pragma unroll
    for (int dt = 0; dt < 4; ++dt) {
      float val = accO[dt][r] * inv;
      AO[(size_t)(b_ * SEQ + sq) * DM + h_ * DKH + dt * 16 + l15] = f2bf(val);
    }
  }
}

extern "C" void kernel_launch(void* const* d_in, const int* in_sizes, int n_in,
                              void* d_out, int out_size, void* d_ws, size_t ws_size,
                              hipStream_t stream) {
  (void)in_sizes; (void)n_in; (void)out_size; (void)ws_size;
  const float* queries = (const float*)d_in[0];
  const float* keys = (const float*)d_in[1];
  const float* values = (const float*)d_in[2];
  const float* Wq = (const float*)d_in[3];
  const float* bq = (const float*)d_in[4];
  const float* Wk = (const float*)d_in[5];
  const float* bk = (const float*)d_in[6];
  const float* Wv = (const float*)d_in[7];
  const float* bv = (const float*)d_in[8];
  const float* Wo = (const float*)d_in[9];
  const float* bo = (const float*)d_in[10];
  float* out = (float*)d_out;

  char* ws = (char*)d_ws;
  unsigned short* wt_q = (unsigned short*)(ws + 0 * (1u << 21));
  unsigned short* wt_k = (unsigned short*)(ws + 1 * (1u << 21));
  unsigned short* wt_v = (unsigned short*)(ws + 2 * (1u << 21));
  unsigned short* wt_o = (unsigned short*)(ws + 3 * (1u << 21));
  unsigned short* Qb = (unsigned short*)(ws + (8u << 20));
  unsigned short* Kb = (unsigned short*)(ws + (24u << 20));
  unsigned short* Vt = (unsigned short*)(ws + (40u << 20));
  unsigned short* AO = (unsigned short*)(ws + (56u << 20));
  // total ws use: 72 MiB

  dim3 tgrid(32, 32);
  wcast_t<<<tgrid, 256, 0, stream>>>(Wq, wt_q);
  wcast_t<<<tgrid, 256, 0, stream>>>(Wk, wt_k);
  wcast_t<<<tgrid, 256, 0, stream>>>(Wv, wt_v);
  wcast_t<<<tgrid, 256, 0, stream>>>(Wo, wt_o);

  const float SQ = 0.125f * 1.4426950408889634f;  // fold 1/sqrt(64) and log2(e) into Q
  gemm128<0, 0><<<512, 256, 0, stream>>>(queries, wt_q, bq, Qb, SQ);
  gemm128<0, 0><<<512, 256, 0, stream>>>(keys, wt_k, bk, Kb, 1.0f);
  gemm128<1, 0><<<512, 256, 0, stream>>>(values, wt_v, bv, Vt, 1.0f);
  attn_fwd<<<dim3(32, 64), 256, 0, stream>>>(Qb, Kb, Vt, AO);
  gemm128<2, 1><<<512, 256, 0, stream>>>(AO, wt_o, bo, out, 1.0f);
}

// Round 3
// 400.988 us; speedup vs baseline: 1.5615x; 1.5405x over previous
//
#include <hip/hip_runtime.h>
#include <hip/hip_bf16.h>
#include <stdint.h>

#define DM 1024
#define DKH 64
#define NH 16
#define NB 4
#define SEQ 2048

typedef __attribute__((ext_vector_type(8))) short bf16x8;
typedef __attribute__((ext_vector_type(8))) unsigned short ushort8;
typedef __attribute__((ext_vector_type(4))) float f32x4;

__device__ inline unsigned short f2bf(float f) {
  union { float f; unsigned u; } c; c.f = f;
  unsigned u = c.u;
  u += 0x7fff + ((u >> 16) & 1);   // round-to-nearest-even
  return (unsigned short)(u >> 16);
}

// ---------- weight transpose + cast: Wt[n][k] = bf16(W[k][n]), 1024x1024 ----------
__global__ __launch_bounds__(256) void wcast_t(const float* __restrict__ W,
                                               unsigned short* __restrict__ Wt) {
  __shared__ float tile[32][33];
  int bk = blockIdx.x * 32, bn = blockIdx.y * 32;
  int tx = threadIdx.x & 31, ty = threadIdx.x >> 5;  // ty 0..7
#pragma unroll
  for (int i = 0; i < 4; ++i)
    tile[ty + 8 * i][tx] = W[(size_t)(bk + ty + 8 * i) * DM + bn + tx];
  __syncthreads();
#pragma unroll
  for (int i = 0; i < 4; ++i)
    Wt[(size_t)(bn + ty + 8 * i) * DM + bk + tx] = f2bf(tile[tx][ty + 8 * i]);
}

// ---------- 128x128 tile bf16 GEMM, M=8192 N=1024 K=1024 ----------
template <int EPI, int ABF16>
__global__ __launch_bounds__(256) void gemm128(const void* __restrict__ Av,
                                               const unsigned short* __restrict__ Bt,
                                               const float* __restrict__ bias,
                                               void* __restrict__ Cv, float scale) {
  __shared__ __align__(16) unsigned short As[128][32];
  __shared__ __align__(16) unsigned short Bs[128][32];
  const int K = DM;
  int t = threadIdx.x;
  int wave = t >> 6, lane = t & 63;
  int wr = wave >> 1, wc = wave & 1;
  int l15 = lane & 15, g = lane >> 4;
  int tm = blockIdx.x >> 3, tn = blockIdx.x & 7;  // N/128 = 8
  int rowBase = tm * 128, colBase = tn * 128;

  f32x4 acc[4][4];
#pragma unroll
  for (int mi = 0; mi < 4; ++mi)
#pragma unroll
    for (int ni = 0; ni < 4; ++ni) acc[mi][ni] = (f32x4){0.f, 0.f, 0.f, 0.f};

  int srow = t >> 2;        // 0..63
  int skb = (t & 3) * 8;    // 0,8,16,24

  for (int kt = 0; kt < K; kt += 32) {
    __syncthreads();
#pragma unroll
    for (int i = 0; i < 2; ++i) {
      int row = srow + i * 64;
      if (ABF16) {
        ushort8 v = *reinterpret_cast<const ushort8*>(
            (const unsigned short*)Av + (size_t)(rowBase + row) * K + kt + skb);
        *reinterpret_cast<ushort8*>(&As[row][skb]) = v;
      } else {
        const float* Af = (const float*)Av + (size_t)(rowBase + row) * K + kt + skb;
        float4 x = *reinterpret_cast<const float4*>(Af);
        float4 y = *reinterpret_cast<const float4*>(Af + 4);
        ushort8 v;
        v[0] = f2bf(x.x); v[1] = f2bf(x.y); v[2] = f2bf(x.z); v[3] = f2bf(x.w);
        v[4] = f2bf(y.x); v[5] = f2bf(y.y); v[6] = f2bf(y.z); v[7] = f2bf(y.w);
        *reinterpret_cast<ushort8*>(&As[row][skb]) = v;
      }
      ushort8 w = *reinterpret_cast<const ushort8*>(
          Bt + (size_t)(colBase + row) * K + kt + skb);
      *reinterpret_cast<ushort8*>(&Bs[row][skb]) = w;
    }
    __syncthreads();

    bf16x8 af[4], bfr[4];
#pragma unroll
    for (int mi = 0; mi < 4; ++mi)
      af[mi] = *reinterpret_cast<const bf16x8*>(&As[wr * 64 + mi * 16 + l15][g * 8]);
#pragma unroll
    for (int ni = 0; ni < 4; ++ni)
      bfr[ni] = *reinterpret_cast<const bf16x8*>(&Bs[wc * 64 + ni * 16 + l15][g * 8]);
#pragma unroll
    for (int mi = 0; mi < 4; ++mi)
#pragma unroll
      for (int ni = 0; ni < 4; ++ni)
        acc[mi][ni] = __builtin_amdgcn_mfma_f32_16x16x32_bf16(af[mi], bfr[ni],
                                                              acc[mi][ni], 0, 0, 0);
  }

#pragma unroll
  for (int ni = 0; ni < 4; ++ni) {
    int col = colBase + wc * 64 + ni * 16 + l15;
    float bv = bias[col];
#pragma unroll
    for (int mi = 0; mi < 4; ++mi) {
#pragma unroll
      for (int r = 0; r < 4; ++r) {
        int row = rowBase + wr * 64 + mi * 16 + g * 4 + r;
        float val = (acc[mi][ni][r] + bv) * scale;
        if (EPI == 0) {
          int b_ = row >> 11, s_ = row & 2047;
          int h_ = col >> 6, d_ = col & 63;
          ((unsigned short*)Cv)[(size_t)((b_ * NH + h_) * SEQ + s_) * DKH + d_] = f2bf(val);
        } else if (EPI == 1) {
          int b_ = row >> 11, s_ = row & 2047;
          int h_ = col >> 6, d_ = col & 63;
          ((unsigned short*)Cv)[(size_t)((b_ * NH + h_) * DKH + d_) * SEQ + s_] = f2bf(val);
        } else {
          ((float*)Cv)[(size_t)row * DM + col] = val;
        }
      }
    }
  }
}

// ---------- flash attention (swapped QK^T, lane-local softmax, SW-pipelined) ----------
// Q,K [BH][S][64] bf16 (Q pre-scaled by 0.125*log2e), Vt [BH][64][S] bf16,
// AO [B][S][H*64] bf16.
// Per wave: 32 q-rows (2 x 16-row fragments sharing each K/V fragment).
// K/V register double-buffered with prefetch distance 1 (explicit A/B bufs).
__global__ __launch_bounds__(256) void attn_fwd(const unsigned short* __restrict__ Qb,
                                                const unsigned short* __restrict__ Kb,
                                                const unsigned short* __restrict__ Vt,
                                                unsigned short* __restrict__ AO) {
  // row stride 40 shorts = 80 B: 16B-aligned rows, ~2-way (free) bank aliasing
  __shared__ __align__(16) unsigned short Plds[4][2][16][40];
  int t = threadIdx.x;
  int wave = t >> 6, lane = t & 63;
  int l15 = lane & 15, g = lane >> 4;
  int qtile = blockIdx.x;  // 0..15
  int bh = blockIdx.y;     // 0..63
  const size_t baseQK = (size_t)bh * SEQ * DKH;
  const size_t baseV = (size_t)bh * DKH * SEQ;
  int q0 = qtile * 128 + wave * 32;

  bf16x8 aQ[2][2];
#pragma unroll
  for (int qf = 0; qf < 2; ++qf)
#pragma unroll
    for (int dh = 0; dh < 2; ++dh)
      aQ[qf][dh] = *reinterpret_cast<const bf16x8*>(
          Qb + baseQK + (size_t)(q0 + qf * 16 + l15) * DKH + dh * 32 + g * 8);

  float m[2] = {-1e30f, -1e30f}, lsum[2] = {0.f, 0.f};
  f32x4 accO[2][4];
#pragma unroll
  for (int qf = 0; qf < 2; ++qf)
#pragma unroll
    for (int dt = 0; dt < 4; ++dt) accO[qf][dt] = (f32x4){0.f, 0.f, 0.f, 0.f};

  const unsigned short* Kp = Kb + baseQK + (size_t)l15 * DKH + g * 8;
  const unsigned short* Vp = Vt + baseV + (size_t)l15 * SEQ + g * 8;

  bf16x8 kA[2][2], kB[2][2], vA[4], vB[4];

  auto loadK = [&](bf16x8 (&kf)[2][2], int s0) {
#pragma unroll
    for (int tt = 0; tt < 2; ++tt)
#pragma unroll
      for (int dh = 0; dh < 2; ++dh)
        kf[tt][dh] = *reinterpret_cast<const bf16x8*>(
            Kp + (size_t)(s0 + tt * 16) * DKH + dh * 32);
  };
  auto loadV = [&](bf16x8 (&vf)[4], int s0) {
#pragma unroll
    for (int dt = 0; dt < 4; ++dt)
      vf[dt] = *reinterpret_cast<const bf16x8*>(Vp + (size_t)(dt * 16) * SEQ + s0);
  };

  auto step = [&](const bf16x8 (&kf)[2][2], const bf16x8 (&vf)[4], int s0) {
    f32x4 sc[2][2];
#pragma unroll
    for (int qf = 0; qf < 2; ++qf)
#pragma unroll
      for (int tt = 0; tt < 2; ++tt) {
        f32x4 z = (f32x4){0.f, 0.f, 0.f, 0.f};
#pragma unroll
        for (int dh = 0; dh < 2; ++dh)
          z = __builtin_amdgcn_mfma_f32_16x16x32_bf16(kf[tt][dh], aQ[qf][dh], z, 0, 0, 0);
        sc[qf][tt] = z;
      }
#pragma unroll
    for (int qf = 0; qf < 2; ++qf) {
      float vm = fmaxf(
          fmaxf(fmaxf(sc[qf][0][0], sc[qf][0][1]), fmaxf(sc[qf][0][2], sc[qf][0][3])),
          fmaxf(fmaxf(sc[qf][1][0], sc[qf][1][1]), fmaxf(sc[qf][1][2], sc[qf][1][3])));
      vm = fmaxf(vm, __shfl_xor(vm, 16));
      vm = fmaxf(vm, __shfl_xor(vm, 32));  // row-max of q=l15, uniform across g
      if (__any(vm > m[qf] + 8.f)) {       // defer-max (T13)
        float mnew = fmaxf(m[qf], vm);
        float alpha = __builtin_amdgcn_exp2f(m[qf] - mnew);
        m[qf] = mnew;
        lsum[qf] *= alpha;
        float ar[4];
#pragma unroll
        for (int r = 0; r < 4; ++r) ar[r] = __shfl(alpha, g * 4 + r);
#pragma unroll
        for (int dt = 0; dt < 4; ++dt)
#pragma unroll
          for (int r = 0; r < 4; ++r) accO[qf][dt][r] *= ar[r];
      }
      float pv[8];
#pragma unroll
      for (int tt = 0; tt < 2; ++tt)
#pragma unroll
        for (int r = 0; r < 4; ++r)
          pv[tt * 4 + r] = __builtin_amdgcn_exp2f(sc[qf][tt][r] - m[qf]);
      lsum[qf] +=
          ((pv[0] + pv[1]) + (pv[2] + pv[3])) + ((pv[4] + pv[5]) + (pv[6] + pv[7]));
#pragma unroll
      for (int tt = 0; tt < 2; ++tt)
#pragma unroll
        for (int s = 0; s < 2; ++s) {
          unsigned w;
          asm("v_cvt_pk_bf16_f32 %0, %1, %2"
              : "=v"(w)
              : "v"(pv[tt * 4 + 2 * s]), "v"(pv[tt * 4 + 2 * s + 1]));
          *reinterpret_cast<unsigned*>(&Plds[wave][qf][l15][tt * 16 + g * 4 + 2 * s]) = w;
        }
    }
    asm volatile("s_waitcnt lgkmcnt(0)" ::: "memory");
#pragma unroll
    for (int qf = 0; qf < 2; ++qf) {
      bf16x8 aP = *reinterpret_cast<const bf16x8*>(&Plds[wave][qf][l15][g * 8]);
#pragma unroll
      for (int dt = 0; dt < 4; ++dt)
        accO[qf][dt] =
            __builtin_amdgcn_mfma_f32_16x16x32_bf16(aP, vf[dt], accO[qf][dt], 0, 0, 0);
    }
  };

  loadK(kA, 0);
  loadV(vA, 0);
  for (int pc = 0; pc < SEQ / 32; pc += 2) {
    int s0 = pc * 32;
    loadK(kB, s0 + 32);   // prefetch chunk pc+1 (pc+1 <= 63 always)
    loadV(vB, s0 + 32);
    step(kA, vA, s0);
    if (pc + 2 < SEQ / 32) {
      loadK(kA, s0 + 64);  // prefetch chunk pc+2
      loadV(vA, s0 + 64);
    }
    step(kB, vB, s0 + 32);
  }

  int b_ = bh >> 4, h_ = bh & 15;
#pragma unroll
  for (int qf = 0; qf < 2; ++qf) {
    float ls = lsum[qf];
    ls += __shfl_xor(ls, 16);
    ls += __shfl_xor(ls, 32);
#pragma unroll
    for (int r = 0; r < 4; ++r) {
      float lr = __shfl(ls, g * 4 + r);
      float inv = 1.f / lr;
      int sq = q0 + qf * 16 + g * 4 + r;
#pragma unroll
      for (int dt = 0; dt < 4; ++dt) {
        float val = accO[qf][dt][r] * inv;
        AO[(size_t)(b_ * SEQ + sq) * DM + h_ * DKH + dt * 16 + l15] = f2bf(val);
      }
    }
  }
}

extern "C" void kernel_launch(void* const* d_in, const int* in_sizes, int n_in,
                              void* d_out, int out_size, void* d_ws, size_t ws_size,
                              hipStream_t stream) {
  (void)in_sizes; (void)n_in; (void)out_size; (void)ws_size;
  const float* queries = (const float*)d_in[0];
  const float* keys = (const float*)d_in[1];
  const float* values = (const float*)d_in[2];
  const float* Wq = (const float*)d_in[3];
  const float* bq = (const float*)d_in[4];
  const float* Wk = (const float*)d_in[5];
  const float* bk = (const float*)d_in[6];
  const float* Wv = (const float*)d_in[7];
  const float* bv = (const float*)d_in[8];
  const float* Wo = (const float*)d_in[9];
  const float* bo = (const float*)d_in[10];
  float* out = (float*)d_out;

  char* ws = (char*)d_ws;
  unsigned short* wt_q = (unsigned short*)(ws + 0 * (1u << 21));
  unsigned short* wt_k = (unsigned short*)(ws + 1 * (1u << 21));
  unsigned short* wt_v = (unsigned short*)(ws + 2 * (1u << 21));
  unsigned short* wt_o = (unsigned short*)(ws + 3 * (1u << 21));
  unsigned short* Qb = (unsigned short*)(ws + (8u << 20));
  unsigned short* Kb = (unsigned short*)(ws + (24u << 20));
  unsigned short* Vt = (unsigned short*)(ws + (40u << 20));
  unsigned short* AO = (unsigned short*)(ws + (56u << 20));
  // total ws use: 72 MiB

  dim3 tgrid(32, 32);
  wcast_t<<<tgrid, 256, 0, stream>>>(Wq, wt_q);
  wcast_t<<<tgrid, 256, 0, stream>>>(Wk, wt_k);
  wcast_t<<<tgrid, 256, 0, stream>>>(Wv, wt_v);
  wcast_t<<<tgrid, 256, 0, stream>>>(Wo, wt_o);

  const float SQ = 0.125f * 1.4426950408889634f;  // fold 1/sqrt(64) and log2(e) into Q
  gemm128<0, 0><<<512, 256, 0, stream>>>(queries, wt_q, bq, Qb, SQ);
  gemm128<0, 0><<<512, 256, 0, stream>>>(keys, wt_k, bk, Kb, 1.0f);
  gemm128<1, 0><<<512, 256, 0, stream>>>(values, wt_v, bv, Vt, 1.0f);
  attn_fwd<<<dim3(16, 64), 256, 0, stream>>>(Qb, Kb, Vt, AO);
  gemm128<2, 1><<<512, 256, 0, stream>>>(AO, wt_o, bo, out, 1.0f);
}